// Round 1
// baseline (335.252 us; speedup 1.0000x reference)
//
#include <hip/hip_runtime.h>

#define EPSF 1e-8f
#define HALF_PI 1.5707963267948966f
#define TWO_PI  6.283185307179586f

// image layout: (B=16, C=3, H*W = 1<<20), fp32.
// Each thread processes 4 consecutive pixels of one (b) image -> float4
// loads from the R, G, B planes and float4 stores to the X, Y, Z planes.
__global__ __launch_bounds__(256) void rgb2hvi_kernel(
    const float* __restrict__ img,
    const float* __restrict__ kptr,
    float* __restrict__ out,
    int n4)  // total pixels / 4
{
    int tid = blockIdx.x * blockDim.x + threadIdx.x;
    if (tid >= n4) return;

    const float k = kptr[0];          // uniform -> scalar load, L2-cached

    const int HW = 1 << 20;           // 1024*1024
    int i = tid << 2;                 // flat pixel index over (b, p)
    int bidx = i >> 20;               // batch
    int p = i & (HW - 1);             // pixel within image
    long long base = (long long)bidx * (3LL * HW) + p;

    const float4 r4 = *(const float4*)(img + base);
    const float4 g4 = *(const float4*)(img + base + HW);
    const float4 b4 = *(const float4*)(img + base + 2 * HW);

    float rr[4] = {r4.x, r4.y, r4.z, r4.w};
    float gg[4] = {g4.x, g4.y, g4.z, g4.w};
    float bb[4] = {b4.x, b4.y, b4.z, b4.w};
    float X[4], Y[4], Z[4];

#pragma unroll
    for (int j = 0; j < 4; ++j) {
        float r = rr[j], g = gg[j], b = bb[j];

        float v  = fmaxf(r, fmaxf(g, b));
        float mn = fminf(r, fminf(g, b));
        float denom = v - mn + EPSF;
        float invd = __builtin_amdgcn_rcpf(denom);   // ~2^-22 rel err, fine @2e-2 tol

        // hue candidates
        float hr = (g - b) * invd;                   // in (-1, 1)
        hr = (hr < 0.0f) ? hr + 6.0f : hr;           // == floor-mod 6 on (-1,1)
        float hg = 2.0f + (b - r) * invd;
        float hb = 4.0f + (r - g) * invd;

        // jnp.where chain, last-wins priority: min > r > g > b
        float hue = (b  == v) ? hb   : 0.0f;
        hue       = (g  == v) ? hg   : hue;
        hue       = (r  == v) ? hr   : hue;
        hue       = (mn == v) ? 0.0f : hue;
        hue *= (1.0f / 6.0f);

        float sat = (v == 0.0f) ? 0.0f
                                : (v - mn) * __builtin_amdgcn_rcpf(v + EPSF);

        // color_sensitive = (sin(v*pi/2) + eps)^k ; base > 0 always
        float cs = __powf(__sinf(v * HALF_PI) + EPSF, k);

        float ang = TWO_PI * hue;
        float cx = __cosf(ang);
        float cy = __sinf(ang);

        float s = cs * sat;
        X[j] = s * cx;
        Y[j] = s * cy;
        Z[j] = v;
    }

    *(float4*)(out + base)          = make_float4(X[0], X[1], X[2], X[3]);
    *(float4*)(out + base + HW)     = make_float4(Y[0], Y[1], Y[2], Y[3]);
    *(float4*)(out + base + 2 * HW) = make_float4(Z[0], Z[1], Z[2], Z[3]);
}

extern "C" void kernel_launch(void* const* d_in, const int* in_sizes, int n_in,
                              void* d_out, int out_size, void* d_ws, size_t ws_size,
                              hipStream_t stream) {
    const float* img  = (const float*)d_in[0];
    const float* kptr = (const float*)d_in[1];
    float* out = (float*)d_out;

    int total = in_sizes[0];          // 16*3*1024*1024
    int pixels = total / 3;           // 16*1024*1024
    int n4 = pixels / 4;              // 4194304

    int block = 256;
    int grid = (n4 + block - 1) / block;  // 16384
    rgb2hvi_kernel<<<grid, block, 0, stream>>>(img, kptr, out, n4);
}